// Round 5
// baseline (289.870 us; speedup 1.0000x reference)
//
#include <hip/hip_runtime.h>
#include <math.h>

// OnlineTripletLoss on MI355X — Round 5.
// R4: 194.6 us; fused kernel 124 us at 22% occupancy (2 blocks/CU, 65KB LDS) — barrier
//     drains unhidden, MfmaUtil 17%.
// Changes:
//  (1) 128x128 tile, grid 1024 = exactly 4 blocks/CU (LDS ~36KB, launch_bounds(256,4)
//      caps VGPR at 128 -> co-residency for the spin barrier is guaranteed).
//  (2) global_load_lds 16B staging with XOR-swizzled LDS layout
//      (chunk_phys = chunk_log ^ ((row^(row>>2))&3)): DMA writes contiguous
//      (conflict-free), frag ds_read_b128 spreads 32 lanes over all 32 banks.
//  (3) prep kernel fuses init + sq + f32->hi/lo f16 convert (5 launches -> 3).
// ws: sq[N] | hp[N] | hn_fall[N] | hn_semi[N] | bar | pad | ehl[N][2D] f16

constexpr float MARGIN = 0.3f;

typedef _Float16 half8    __attribute__((ext_vector_type(8)));
typedef float    floatx16 __attribute__((ext_vector_type(16)));

#define GLD_LDS16(gp, lp)                                                              \
    __builtin_amdgcn_global_load_lds(                                                  \
        (const __attribute__((address_space(1))) void*)(gp),                           \
        (__attribute__((address_space(3))) void*)(lp), 16, 0, 0)

// prep: per row — sq (fp32), hi/lo f16 split, and per-row init of hp/hn arrays.
__global__ __launch_bounds__(256)
void prep_kernel(const float* __restrict__ e, _Float16* __restrict__ ehl,
                 float* __restrict__ sq, unsigned int* __restrict__ hp,
                 unsigned int* __restrict__ hn_fall, unsigned int* __restrict__ hn_semi,
                 unsigned int* __restrict__ bar, int N, int D) {
    const int row  = blockIdx.x * 4 + (threadIdx.x >> 6);
    const int lane = threadIdx.x & 63;
    if (threadIdx.x == 0 && blockIdx.x == 0) bar[0] = 0u;
    if (row >= N) return;
    const float* er = e + (size_t)row * D;
    _Float16* hr = ehl + (size_t)row * 2 * D;
    float s = 0.f;
    for (int k0 = lane * 8; k0 < D; k0 += 512) {
        const float4 x0 = *(const float4*)&er[k0];
        const float4 x1 = *(const float4*)&er[k0 + 4];
        const float xv[8] = {x0.x, x0.y, x0.z, x0.w, x1.x, x1.y, x1.z, x1.w};
        half8 hi, lo;
        #pragma unroll
        for (int j = 0; j < 8; ++j) {
            _Float16 h = (_Float16)xv[j];
            hi[j] = h;
            lo[j] = (_Float16)(xv[j] - (float)h);
            s += xv[j] * xv[j];
        }
        *(half8*)&hr[k0]     = hi;
        *(half8*)&hr[D + k0] = lo;
    }
    #pragma unroll
    for (int off = 32; off; off >>= 1) s += __shfl_down(s, off, 64);
    if (lane == 0) {
        sq[row]      = s;
        hp[row]      = 0u;           // max identity (dist >= 0)
        hn_fall[row] = 0u;
        hn_semi[row] = 0x7f800000u;  // +inf (min identity)
    }
}

// Fused two-phase kernel. Tile 128x128, 4 waves each 64x64 (2x2 of 32x32x16 f16).
// dot = sum_k (hi.hi + hi.lo + lo.hi); acc retained across a grid spin-barrier.
__global__ __launch_bounds__(256, 4)
void fused_kernel(const _Float16* __restrict__ ehl, const int* __restrict__ labels,
                  const float* __restrict__ sq,
                  unsigned int* __restrict__ hp,
                  unsigned int* __restrict__ hn_fall,
                  unsigned int* __restrict__ hn_semi,
                  unsigned int* __restrict__ bar,
                  int N, int D, unsigned int nblocks) {
    constexpr int TM = 128, TN = 128, BK = 32;  // BK halves = 64B per row-chunk, no pad (DMA)
    __shared__ __attribute__((aligned(16))) _Float16 Ah[TM * BK];
    __shared__ __attribute__((aligned(16))) _Float16 Al[TM * BK];
    __shared__ __attribute__((aligned(16))) _Float16 Bh[TN * BK];
    __shared__ __attribute__((aligned(16))) _Float16 Bl[TN * BK];
    __shared__ float sq_r[TM], sq_c[TN], hp_r[TM];
    __shared__ int   lab_r[TM], lab_c[TN];

    const int tid  = threadIdx.x;
    const int lane = tid & 63;
    const int wave = tid >> 6;
    const int wr = (wave >> 1) * 64;     // wave row offset
    const int wc = (wave & 1) * 64;      // wave col offset
    const int mrow = lane & 31;
    const int half_id = lane >> 5;
    const int rowBase = blockIdx.y * TM;
    const int colBase = blockIdx.x * TN;

    if (tid < TM) {
        sq_r[tid]  = sq[rowBase + tid];
        lab_r[tid] = labels[rowBase + tid];
    } else {
        int t = tid - TM;
        sq_c[t]  = sq[colBase + t];
        lab_c[t] = labels[colBase + t];
    }

    floatx16 acc[2][2];
    #pragma unroll
    for (int i = 0; i < 2; ++i)
        #pragma unroll
        for (int j = 0; j < 2; ++j)
            #pragma unroll
            for (int r = 0; r < 16; ++r) acc[i][j][r] = 0.f;

    // staging lane constants: lane -> (row srow, phys chunk lane&3, logical chunk sc)
    const int srow = lane >> 2;                         // 0..15
    const int sc   = (lane & 3) ^ ((srow ^ (srow >> 2)) & 3);
    const int fswz = (mrow ^ (mrow >> 2)) & 3;          // frag-read swizzle (= swz(row), bases %16==0)
    const size_t rs = (size_t)2 * D;

    #pragma unroll 1
    for (int kk = 0; kk < D; kk += BK) {
        __syncthreads();
        #pragma unroll
        for (int h = 0; h < 2; ++h) {                   // wave stages rows [wave*32, +32)
            const int rloc = wave * 32 + h * 16;
            const _Float16* gA = &ehl[(size_t)(rowBase + rloc + srow) * rs + kk + sc * 8];
            const _Float16* gB = &ehl[(size_t)(colBase + rloc + srow) * rs + kk + sc * 8];
            GLD_LDS16(gA,     &Ah[rloc * BK]);
            GLD_LDS16(gA + D, &Al[rloc * BK]);
            GLD_LDS16(gB,     &Bh[rloc * BK]);
            GLD_LDS16(gB + D, &Bl[rloc * BK]);
        }
        __syncthreads();                                // waits vmcnt(0): DMA complete
        #pragma unroll
        for (int ks = 0; ks < 2; ++ks) {
            const int q  = ((ks * 2 + half_id) ^ fswz) * 8;
            const int i0 = (wr + mrow) * BK + q,  i1 = (wr + 32 + mrow) * BK + q;
            const int j0 = (wc + mrow) * BK + q,  j1 = (wc + 32 + mrow) * BK + q;
            const half8 ah0 = *(const half8*)&Ah[i0], ah1 = *(const half8*)&Ah[i1];
            const half8 al0 = *(const half8*)&Al[i0], al1 = *(const half8*)&Al[i1];
            const half8 bh0 = *(const half8*)&Bh[j0], bh1 = *(const half8*)&Bh[j1];
            const half8 bl0 = *(const half8*)&Bl[j0], bl1 = *(const half8*)&Bl[j1];
            acc[0][0] = __builtin_amdgcn_mfma_f32_32x32x16_f16(ah0, bh0, acc[0][0], 0, 0, 0);
            acc[0][1] = __builtin_amdgcn_mfma_f32_32x32x16_f16(ah0, bh1, acc[0][1], 0, 0, 0);
            acc[1][0] = __builtin_amdgcn_mfma_f32_32x32x16_f16(ah1, bh0, acc[1][0], 0, 0, 0);
            acc[1][1] = __builtin_amdgcn_mfma_f32_32x32x16_f16(ah1, bh1, acc[1][1], 0, 0, 0);
            acc[0][0] = __builtin_amdgcn_mfma_f32_32x32x16_f16(ah0, bl0, acc[0][0], 0, 0, 0);
            acc[0][1] = __builtin_amdgcn_mfma_f32_32x32x16_f16(ah0, bl1, acc[0][1], 0, 0, 0);
            acc[1][0] = __builtin_amdgcn_mfma_f32_32x32x16_f16(ah1, bl0, acc[1][0], 0, 0, 0);
            acc[1][1] = __builtin_amdgcn_mfma_f32_32x32x16_f16(ah1, bl1, acc[1][1], 0, 0, 0);
            acc[0][0] = __builtin_amdgcn_mfma_f32_32x32x16_f16(al0, bh0, acc[0][0], 0, 0, 0);
            acc[0][1] = __builtin_amdgcn_mfma_f32_32x32x16_f16(al0, bh1, acc[0][1], 0, 0, 0);
            acc[1][0] = __builtin_amdgcn_mfma_f32_32x32x16_f16(al1, bh0, acc[1][0], 0, 0, 0);
            acc[1][1] = __builtin_amdgcn_mfma_f32_32x32x16_f16(al1, bh1, acc[1][1], 0, 0, 0);
        }
    }

    // per-lane column metadata (C/D layout: col = mrow within each 32-col frag)
    float sqcv[2]; int lcv[2];
    sqcv[0] = sq_c[wc + mrow];      lcv[0] = lab_c[wc + mrow];
    sqcv[1] = sq_c[wc + 32 + mrow]; lcv[1] = lab_c[wc + 32 + mrow];

    // ---- phase 1: hp (hardest positive), hn_fall (hardest negative) row maxima ----
    #pragma unroll
    for (int bi = 0; bi < 2; ++bi) {
        #pragma unroll
        for (int r = 0; r < 16; ++r) {
            const int lrow = wr + bi * 32 + (r & 3) + 8 * (r >> 2) + 4 * half_id;
            const float sqr = sq_r[lrow];
            const int   lr  = lab_r[lrow];
            float d0 = sqrtf(fmaxf(sqr + sqcv[0] - 2.0f * acc[bi][0][r], 1e-12f));
            float d1 = sqrtf(fmaxf(sqr + sqcv[1] - 2.0f * acc[bi][1][r], 1e-12f));
            const bool p0 = (lr == lcv[0]), p1 = (lr == lcv[1]);
            float vp = fmaxf(p0 ? d0 : 0.f, p1 ? d1 : 0.f);
            float vn = fmaxf(p0 ? 0.f : d0, p1 ? 0.f : d1);
            #pragma unroll
            for (int off = 16; off; off >>= 1) {   // reduce over 32 cols (stays in half-wave)
                vp = fmaxf(vp, __shfl_xor(vp, off, 64));
                vn = fmaxf(vn, __shfl_xor(vn, off, 64));
            }
            if (mrow == 0) {
                atomicMax(&hp[rowBase + lrow],      __float_as_uint(vp));
                atomicMax(&hn_fall[rowBase + lrow], __float_as_uint(vn));
            }
        }
    }

    // ---- grid spin barrier (1024 blocks co-resident: 4/CU by construction) ----
    __syncthreads();                 // each wave drains its atomics before signaling
    if (tid == 0) {
        __threadfence();
        atomicAdd(bar, 1u);
        while (atomicAdd(bar, 0u) < nblocks) __builtin_amdgcn_s_sleep(8);
        __threadfence();
    }
    __syncthreads();
    if (tid < TM)                    // device-scope read of completed hp
        hp_r[tid] = __uint_as_float(atomicMax(&hp[rowBase + tid], 0u));
    __syncthreads();

    // ---- phase 2: hn_semi = min{d : neg, d > hp} from retained acc ----
    #pragma unroll
    for (int bi = 0; bi < 2; ++bi) {
        #pragma unroll
        for (int r = 0; r < 16; ++r) {
            const int lrow = wr + bi * 32 + (r & 3) + 8 * (r >> 2) + 4 * half_id;
            const float sqr = sq_r[lrow];
            const int   lr  = lab_r[lrow];
            const float hpv = hp_r[lrow];
            float d0 = sqrtf(fmaxf(sqr + sqcv[0] - 2.0f * acc[bi][0][r], 1e-12f));
            float d1 = sqrtf(fmaxf(sqr + sqcv[1] - 2.0f * acc[bi][1][r], 1e-12f));
            const bool c0 = (lr != lcv[0]) && (d0 > hpv);
            const bool c1 = (lr != lcv[1]) && (d1 > hpv);
            float vm = fminf(c0 ? d0 : __builtin_inff(), c1 ? d1 : __builtin_inff());
            #pragma unroll
            for (int off = 16; off; off >>= 1)
                vm = fminf(vm, __shfl_xor(vm, off, 64));
            if (mrow == 0)
                atomicMin(&hn_semi[rowBase + lrow], __float_as_uint(vm));
        }
    }
}

__global__ void final_kernel(const unsigned int* __restrict__ hp,
                             const unsigned int* __restrict__ hn_fall,
                             const unsigned int* __restrict__ hn_semi,
                             float* __restrict__ out, int N) {
    __shared__ float ssum[256];
    __shared__ int   scnt[256];
    __shared__ int   sany[256];
    int any = 0;
    for (int i = threadIdx.x; i < N; i += 256) {
        float h  = __uint_as_float(hp[i]);
        float hs = __uint_as_float(hn_semi[i]);
        any |= (hs < h + MARGIN) ? 1 : 0;   // exists semi-hard pair in this row
    }
    sany[threadIdx.x] = any;
    __syncthreads();
    for (int s = 128; s; s >>= 1) {
        if (threadIdx.x < (unsigned)s) sany[threadIdx.x] |= sany[threadIdx.x + s];
        __syncthreads();
    }
    const bool has_semi = sany[0] != 0;
    float sum = 0.f; int valid = 0;
    for (int i = threadIdx.x; i < N; i += 256) {
        float h  = __uint_as_float(hp[i]);
        float hn = has_semi ? __uint_as_float(hn_semi[i]) : __uint_as_float(hn_fall[i]);
        float t  = fmaxf(h - hn + MARGIN, 0.f);
        if (!(t > 0.f)) t = 0.f;            // -inf guard (hn=+inf rows)
        sum += t;
        valid += (t > 0.f) ? 1 : 0;
    }
    ssum[threadIdx.x] = sum; scnt[threadIdx.x] = valid;
    __syncthreads();
    for (int s = 128; s; s >>= 1) {
        if (threadIdx.x < (unsigned)s) {
            ssum[threadIdx.x] += ssum[threadIdx.x + s];
            scnt[threadIdx.x] += scnt[threadIdx.x + s];
        }
        __syncthreads();
    }
    if (threadIdx.x == 0) {
        float total = ssum[0]; int v = scnt[0];
        out[0] = (v > 0) ? (total / (float)v) : (total / (float)N);
    }
}

extern "C" void kernel_launch(void* const* d_in, const int* in_sizes, int n_in,
                              void* d_out, int out_size, void* d_ws, size_t ws_size,
                              hipStream_t stream) {
    const float* e      = (const float*)d_in[0];
    const int*   labels = (const int*)d_in[1];
    const int N = in_sizes[1];
    const int D = in_sizes[0] / N;
    float* out = (float*)d_out;

    float*        sq      = (float*)d_ws;
    unsigned int* hp      = (unsigned int*)d_ws + N;
    unsigned int* hn_fall = hp + N;
    unsigned int* hn_semi = hn_fall + N;
    unsigned int* bar     = hn_semi + N;

    const size_t small_bytes = ((size_t)(4 * N + 1) * 4 + 255) & ~(size_t)255;
    _Float16* ehl = (_Float16*)((char*)d_ws + small_bytes);

    prep_kernel<<<N / 4, 256, 0, stream>>>(e, ehl, sq, hp, hn_fall, hn_semi, bar, N, D);

    dim3 grid(N / 128, N / 128);   // 32 x 32 = 1024 blocks = 4 per CU, co-resident
    fused_kernel<<<grid, 256, 0, stream>>>(ehl, labels, sq, hp, hn_fall, hn_semi, bar,
                                           N, D, grid.x * grid.y);
    final_kernel<<<1, 256, 0, stream>>>(hp, hn_fall, hn_semi, out, N);
}

// Round 6
// 270.460 us; speedup vs baseline: 1.0718x; 1.0718x over previous
//
#include <hip/hip_runtime.h>
#include <math.h>

// OnlineTripletLoss on MI355X — Round 6.
// R5: 290 us. global_load_lds with a 16-rows-x-64B gather per instruction split into
//     ~16 sub-transactions each -> DMA issue/latency bound (MfmaUtil 9%, both pipes idle).
//     R3 (101 us, same grid/atomics) proves atomics/barrier are not the problem.
// Change: pre-tile embeddings into panel format pan[p][kc][r][8] (p=128-row panel,
//     kc = 16B k-chunk, kc<64 hi / kc>=64 lo, r=row). Every DMA is now lane-contiguous
//     1KB global -> LDS [kc][r] (= MFMA frag layout, conflict-free reads), the
//     m97-validated pattern. Hot loop structure otherwise identical to R5.
// ws: sq[N] | hp[N] | hn_fall[N] | hn_semi[N] | bar | pad | pan[N*2D] f16

constexpr float MARGIN = 0.3f;

typedef _Float16 half8    __attribute__((ext_vector_type(8)));
typedef float    floatx16 __attribute__((ext_vector_type(16)));

#define GLD_LDS16(gp, lp)                                                              \
    __builtin_amdgcn_global_load_lds(                                                  \
        (const __attribute__((address_space(1))) void*)(gp),                           \
        (__attribute__((address_space(3))) void*)(lp), 16, 0, 0)

// sq + per-row init (one wave per row)
__global__ __launch_bounds__(256)
void sq_init_kernel(const float* __restrict__ e, float* __restrict__ sq,
                    unsigned int* __restrict__ hp, unsigned int* __restrict__ hn_fall,
                    unsigned int* __restrict__ hn_semi, unsigned int* __restrict__ bar,
                    int N, int D) {
    const int row  = blockIdx.x * 4 + (threadIdx.x >> 6);
    const int lane = threadIdx.x & 63;
    if (threadIdx.x == 0 && blockIdx.x == 0) bar[0] = 0u;
    if (row >= N) return;
    const float* er = e + (size_t)row * D;
    float s = 0.f;
    for (int k0 = lane * 8; k0 < D; k0 += 512) {
        const float4 x0 = *(const float4*)&er[k0];
        const float4 x1 = *(const float4*)&er[k0 + 4];
        s += x0.x*x0.x + x0.y*x0.y + x0.z*x0.z + x0.w*x0.w
           + x1.x*x1.x + x1.y*x1.y + x1.z*x1.z + x1.w*x1.w;
    }
    #pragma unroll
    for (int off = 32; off; off >>= 1) s += __shfl_down(s, off, 64);
    if (lane == 0) {
        sq[row]      = s;
        hp[row]      = 0u;           // max identity (dist >= 0)
        hn_fall[row] = 0u;
        hn_semi[row] = 0x7f800000u;  // +inf (min identity)
    }
}

// panel format: pan[p][kc][r][8] halves, kc in [0,128): kc<64 = hi chunk of k-window
// kc*8, kc>=64 = lo chunk of (kc-64)*8. 8 panels-slices per block (grid = 32*8).
__global__ __launch_bounds__(256)
void panel_kernel(const float* __restrict__ e, _Float16* __restrict__ pan,
                  int N, int D) {
    const int p      = blockIdx.x >> 3;
    const int kwBase = (blockIdx.x & 7) * 8;
    #pragma unroll
    for (int it = 0; it < 4; ++it) {
        const int idx = it * 256 + threadIdx.x;   // 0..1023 = 8 kw x 128 r
        const int kw  = kwBase + (idx >> 7);
        const int r   = idx & 127;
        const float* src = &e[(size_t)(p * 128 + r) * D + kw * 8];
        const float4 x0 = *(const float4*)src;
        const float4 x1 = *(const float4*)(src + 4);
        const float xv[8] = {x0.x, x0.y, x0.z, x0.w, x1.x, x1.y, x1.z, x1.w};
        half8 hi, lo;
        #pragma unroll
        for (int j = 0; j < 8; ++j) {
            _Float16 h = (_Float16)xv[j];
            hi[j] = h;
            lo[j] = (_Float16)(xv[j] - (float)h);
        }
        *(half8*)&pan[((size_t)(p * 128 + kw) * 128 + r) * 8]      = hi;
        *(half8*)&pan[((size_t)(p * 128 + 64 + kw) * 128 + r) * 8] = lo;
    }
}

// Fused two-phase kernel. Tile 128x128, 4 waves each 64x64 (2x2 of 32x32x16 f16).
// dot = sum_k (hi.hi + hi.lo + lo.hi); acc retained across a grid spin-barrier.
__global__ __launch_bounds__(256, 4)
void fused_kernel(const _Float16* __restrict__ pan, const int* __restrict__ labels,
                  const float* __restrict__ sq,
                  unsigned int* __restrict__ hp,
                  unsigned int* __restrict__ hn_fall,
                  unsigned int* __restrict__ hn_semi,
                  unsigned int* __restrict__ bar,
                  int N, int D, unsigned int nblocks) {
    // LDS frag layout [kcl(8)][r(128)][8 halves]: kcl<4 hi chunks, kcl>=4 lo chunks
    __shared__ __attribute__((aligned(16))) _Float16 As[8 * 128 * 8];
    __shared__ __attribute__((aligned(16))) _Float16 Bs[8 * 128 * 8];
    __shared__ float sq_r[128], sq_c[128], hp_r[128];
    __shared__ int   lab_r[128], lab_c[128];

    const int tid  = threadIdx.x;
    const int lane = tid & 63;
    const int wave = tid >> 6;
    const int wr = (wave >> 1) * 64;     // wave row offset
    const int wc = (wave & 1) * 64;      // wave col offset
    const int mrow = lane & 31;
    const int half_id = lane >> 5;
    const int py = blockIdx.y, px = blockIdx.x;
    const int rowBase = py * 128;
    const int colBase = px * 128;

    if (tid < 128) {
        sq_r[tid]  = sq[rowBase + tid];
        lab_r[tid] = labels[rowBase + tid];
    } else {
        int t = tid - 128;
        sq_c[t]  = sq[colBase + t];
        lab_c[t] = labels[colBase + t];
    }

    floatx16 acc[2][2];
    #pragma unroll
    for (int i = 0; i < 2; ++i)
        #pragma unroll
        for (int j = 0; j < 2; ++j)
            #pragma unroll
            for (int r = 0; r < 16; ++r) acc[i][j][r] = 0.f;

    #pragma unroll 1
    for (int kc0 = 0; kc0 < 64; kc0 += 4) {     // 16 iterations, BK = 32 halves
        __syncthreads();
        // 32 DMAs/block: wave w stages chunk kcl=w for all (ab, hilo, h) combos.
        // global side: lane-contiguous 1KB slab; LDS side: uniform base (+lane*16).
        #pragma unroll
        for (int i = 0; i < 8; ++i) {
            const int ab = i >> 2, hilo = (i >> 1) & 1, h = i & 1;
            const int p  = ab ? px : py;
            const int kc = hilo * 64 + kc0 + wave;
            const _Float16* g = pan + ((size_t)(p * 128 + kc) * 128 + h * 64 + lane) * 8;
            _Float16* l = (ab ? Bs : As) + ((hilo * 4 + wave) * 128 + h * 64) * 8;
            GLD_LDS16(g, l);
        }
        __syncthreads();                          // waits vmcnt(0): DMA complete
        #pragma unroll
        for (int ks = 0; ks < 2; ++ks) {
            const int kh = ks * 2 + half_id;      // hi chunk 0..3 (lo = +4)
            const half8 ah0 = *(const half8*)&As[(kh * 128 + wr + mrow) * 8];
            const half8 ah1 = *(const half8*)&As[(kh * 128 + wr + 32 + mrow) * 8];
            const half8 al0 = *(const half8*)&As[((kh + 4) * 128 + wr + mrow) * 8];
            const half8 al1 = *(const half8*)&As[((kh + 4) * 128 + wr + 32 + mrow) * 8];
            const half8 bh0 = *(const half8*)&Bs[(kh * 128 + wc + mrow) * 8];
            const half8 bh1 = *(const half8*)&Bs[(kh * 128 + wc + 32 + mrow) * 8];
            const half8 bl0 = *(const half8*)&Bs[((kh + 4) * 128 + wc + mrow) * 8];
            const half8 bl1 = *(const half8*)&Bs[((kh + 4) * 128 + wc + 32 + mrow) * 8];
            acc[0][0] = __builtin_amdgcn_mfma_f32_32x32x16_f16(ah0, bh0, acc[0][0], 0, 0, 0);
            acc[0][1] = __builtin_amdgcn_mfma_f32_32x32x16_f16(ah0, bh1, acc[0][1], 0, 0, 0);
            acc[1][0] = __builtin_amdgcn_mfma_f32_32x32x16_f16(ah1, bh0, acc[1][0], 0, 0, 0);
            acc[1][1] = __builtin_amdgcn_mfma_f32_32x32x16_f16(ah1, bh1, acc[1][1], 0, 0, 0);
            acc[0][0] = __builtin_amdgcn_mfma_f32_32x32x16_f16(ah0, bl0, acc[0][0], 0, 0, 0);
            acc[0][1] = __builtin_amdgcn_mfma_f32_32x32x16_f16(ah0, bl1, acc[0][1], 0, 0, 0);
            acc[1][0] = __builtin_amdgcn_mfma_f32_32x32x16_f16(ah1, bl0, acc[1][0], 0, 0, 0);
            acc[1][1] = __builtin_amdgcn_mfma_f32_32x32x16_f16(ah1, bl1, acc[1][1], 0, 0, 0);
            acc[0][0] = __builtin_amdgcn_mfma_f32_32x32x16_f16(al0, bh0, acc[0][0], 0, 0, 0);
            acc[0][1] = __builtin_amdgcn_mfma_f32_32x32x16_f16(al0, bh1, acc[0][1], 0, 0, 0);
            acc[1][0] = __builtin_amdgcn_mfma_f32_32x32x16_f16(al1, bh0, acc[1][0], 0, 0, 0);
            acc[1][1] = __builtin_amdgcn_mfma_f32_32x32x16_f16(al1, bh1, acc[1][1], 0, 0, 0);
        }
    }

    // per-lane column metadata (C/D layout: col = mrow within each 32-col frag)
    float sqcv[2]; int lcv[2];
    sqcv[0] = sq_c[wc + mrow];      lcv[0] = lab_c[wc + mrow];
    sqcv[1] = sq_c[wc + 32 + mrow]; lcv[1] = lab_c[wc + 32 + mrow];

    // ---- phase 1: hp (hardest positive), hn_fall (hardest negative) row maxima ----
    #pragma unroll
    for (int bi = 0; bi < 2; ++bi) {
        #pragma unroll
        for (int r = 0; r < 16; ++r) {
            const int lrow = wr + bi * 32 + (r & 3) + 8 * (r >> 2) + 4 * half_id;
            const float sqr = sq_r[lrow];
            const int   lr  = lab_r[lrow];
            float d0 = sqrtf(fmaxf(sqr + sqcv[0] - 2.0f * acc[bi][0][r], 1e-12f));
            float d1 = sqrtf(fmaxf(sqr + sqcv[1] - 2.0f * acc[bi][1][r], 1e-12f));
            const bool p0 = (lr == lcv[0]), p1 = (lr == lcv[1]);
            float vp = fmaxf(p0 ? d0 : 0.f, p1 ? d1 : 0.f);
            float vn = fmaxf(p0 ? 0.f : d0, p1 ? 0.f : d1);
            #pragma unroll
            for (int off = 16; off; off >>= 1) {   // reduce over 32 cols (half-wave)
                vp = fmaxf(vp, __shfl_xor(vp, off, 64));
                vn = fmaxf(vn, __shfl_xor(vn, off, 64));
            }
            if (mrow == 0) {
                atomicMax(&hp[rowBase + lrow],      __float_as_uint(vp));
                atomicMax(&hn_fall[rowBase + lrow], __float_as_uint(vn));
            }
        }
    }

    // ---- grid spin barrier (1024 blocks co-resident: 4/CU by construction) ----
    __syncthreads();                 // each wave drains its atomics before signaling
    if (tid == 0) {
        __threadfence();
        atomicAdd(bar, 1u);
        while (atomicAdd(bar, 0u) < nblocks) __builtin_amdgcn_s_sleep(8);
        __threadfence();
    }
    __syncthreads();
    if (tid < 128)                   // device-scope read of completed hp
        hp_r[tid] = __uint_as_float(atomicMax(&hp[rowBase + tid], 0u));
    __syncthreads();

    // ---- phase 2: hn_semi = min{d : neg, d > hp} from retained acc ----
    #pragma unroll
    for (int bi = 0; bi < 2; ++bi) {
        #pragma unroll
        for (int r = 0; r < 16; ++r) {
            const int lrow = wr + bi * 32 + (r & 3) + 8 * (r >> 2) + 4 * half_id;
            const float sqr = sq_r[lrow];
            const int   lr  = lab_r[lrow];
            const float hpv = hp_r[lrow];
            float d0 = sqrtf(fmaxf(sqr + sqcv[0] - 2.0f * acc[bi][0][r], 1e-12f));
            float d1 = sqrtf(fmaxf(sqr + sqcv[1] - 2.0f * acc[bi][1][r], 1e-12f));
            const bool c0 = (lr != lcv[0]) && (d0 > hpv);
            const bool c1 = (lr != lcv[1]) && (d1 > hpv);
            float vm = fminf(c0 ? d0 : __builtin_inff(), c1 ? d1 : __builtin_inff());
            #pragma unroll
            for (int off = 16; off; off >>= 1)
                vm = fminf(vm, __shfl_xor(vm, off, 64));
            if (mrow == 0)
                atomicMin(&hn_semi[rowBase + lrow], __float_as_uint(vm));
        }
    }
}

__global__ void final_kernel(const unsigned int* __restrict__ hp,
                             const unsigned int* __restrict__ hn_fall,
                             const unsigned int* __restrict__ hn_semi,
                             float* __restrict__ out, int N) {
    __shared__ float ssum[256];
    __shared__ int   scnt[256];
    __shared__ int   sany[256];
    int any = 0;
    for (int i = threadIdx.x; i < N; i += 256) {
        float h  = __uint_as_float(hp[i]);
        float hs = __uint_as_float(hn_semi[i]);
        any |= (hs < h + MARGIN) ? 1 : 0;   // exists semi-hard pair in this row
    }
    sany[threadIdx.x] = any;
    __syncthreads();
    for (int s = 128; s; s >>= 1) {
        if (threadIdx.x < (unsigned)s) sany[threadIdx.x] |= sany[threadIdx.x + s];
        __syncthreads();
    }
    const bool has_semi = sany[0] != 0;
    float sum = 0.f; int valid = 0;
    for (int i = threadIdx.x; i < N; i += 256) {
        float h  = __uint_as_float(hp[i]);
        float hn = has_semi ? __uint_as_float(hn_semi[i]) : __uint_as_float(hn_fall[i]);
        float t  = fmaxf(h - hn + MARGIN, 0.f);
        if (!(t > 0.f)) t = 0.f;            // -inf guard (hn=+inf rows)
        sum += t;
        valid += (t > 0.f) ? 1 : 0;
    }
    ssum[threadIdx.x] = sum; scnt[threadIdx.x] = valid;
    __syncthreads();
    for (int s = 128; s; s >>= 1) {
        if (threadIdx.x < (unsigned)s) {
            ssum[threadIdx.x] += ssum[threadIdx.x + s];
            scnt[threadIdx.x] += scnt[threadIdx.x + s];
        }
        __syncthreads();
    }
    if (threadIdx.x == 0) {
        float total = ssum[0]; int v = scnt[0];
        out[0] = (v > 0) ? (total / (float)v) : (total / (float)N);
    }
}

extern "C" void kernel_launch(void* const* d_in, const int* in_sizes, int n_in,
                              void* d_out, int out_size, void* d_ws, size_t ws_size,
                              hipStream_t stream) {
    const float* e      = (const float*)d_in[0];
    const int*   labels = (const int*)d_in[1];
    const int N = in_sizes[1];
    const int D = in_sizes[0] / N;
    float* out = (float*)d_out;

    float*        sq      = (float*)d_ws;
    unsigned int* hp      = (unsigned int*)d_ws + N;
    unsigned int* hn_fall = hp + N;
    unsigned int* hn_semi = hn_fall + N;
    unsigned int* bar     = hn_semi + N;

    const size_t small_bytes = ((size_t)(4 * N + 1) * 4 + 255) & ~(size_t)255;
    _Float16* pan = (_Float16*)((char*)d_ws + small_bytes);

    sq_init_kernel<<<N / 4, 256, 0, stream>>>(e, sq, hp, hn_fall, hn_semi, bar, N, D);
    panel_kernel<<<(N / 128) * 8, 256, 0, stream>>>(e, pan, N, D);

    dim3 grid(N / 128, N / 128);   // 32 x 32 = 1024 blocks = 4 per CU, co-resident
    fused_kernel<<<grid, 256, 0, stream>>>(pan, labels, sq, hp, hn_fall, hn_semi, bar,
                                           N, D, grid.x * grid.y);
    final_kernel<<<1, 256, 0, stream>>>(hp, hn_fall, hn_semi, out, N);
}

// Round 7
// 184.173 us; speedup vs baseline: 1.5739x; 1.4685x over previous
//
#include <hip/hip_runtime.h>
#include <math.h>

// OnlineTripletLoss on MI355X — Round 7.
// R6: 270 us, fused 204 us, MfmaUtil 10%, all pipes idle. Cross-round isolation:
//   R3 same-GEMM no-barrier = 101 us; fused cost scales with spinner count
//   (512 -> +20 us, 1024 -> +100 us). The global spin barrier's atomicAdd(bar,0)
//   RMW polling serializes 1024 blocks on one line and contends with working
//   blocks' vmem.
// Changes (barrier only, GEMM frozen from R6):
//  (1) per-row-panel barriers bar[py] (128B-spaced): phase 2 of row-panel py only
//      needs the 32 blocks with blockIdx.y==py (hp rows are panel-private).
//  (2) poll with relaxed agent-scope LOAD + s_sleep(32); single RMW to arrive;
//      hp re-read via __hip_atomic_load (no RMW).
// ws: sq[N] | hp[N] | hn_fall[N] | hn_semi[N] | bars[32*32] | pad | pan[N*2D] f16

constexpr float MARGIN = 0.3f;

typedef _Float16 half8    __attribute__((ext_vector_type(8)));
typedef float    floatx16 __attribute__((ext_vector_type(16)));

#define GLD_LDS16(gp, lp)                                                              \
    __builtin_amdgcn_global_load_lds(                                                  \
        (const __attribute__((address_space(1))) void*)(gp),                           \
        (__attribute__((address_space(3))) void*)(lp), 16, 0, 0)

// sq + per-row init (one wave per row) + barrier-counter zeroing
__global__ __launch_bounds__(256)
void sq_init_kernel(const float* __restrict__ e, float* __restrict__ sq,
                    unsigned int* __restrict__ hp, unsigned int* __restrict__ hn_fall,
                    unsigned int* __restrict__ hn_semi, unsigned int* __restrict__ bars,
                    int N, int D) {
    if (blockIdx.x == 0 && threadIdx.x < 32) bars[threadIdx.x * 32] = 0u;
    const int row  = blockIdx.x * 4 + (threadIdx.x >> 6);
    const int lane = threadIdx.x & 63;
    if (row >= N) return;
    const float* er = e + (size_t)row * D;
    float s = 0.f;
    for (int k0 = lane * 8; k0 < D; k0 += 512) {
        const float4 x0 = *(const float4*)&er[k0];
        const float4 x1 = *(const float4*)&er[k0 + 4];
        s += x0.x*x0.x + x0.y*x0.y + x0.z*x0.z + x0.w*x0.w
           + x1.x*x1.x + x1.y*x1.y + x1.z*x1.z + x1.w*x1.w;
    }
    #pragma unroll
    for (int off = 32; off; off >>= 1) s += __shfl_down(s, off, 64);
    if (lane == 0) {
        sq[row]      = s;
        hp[row]      = 0u;           // max identity (dist >= 0)
        hn_fall[row] = 0u;
        hn_semi[row] = 0x7f800000u;  // +inf (min identity)
    }
}

// panel format: pan[p][kc][r][8] halves, kc in [0,128): kc<64 = hi chunk of k-window
// kc*8, kc>=64 = lo chunk of (kc-64)*8. 8 k-window slices per block (grid = 32*8).
__global__ __launch_bounds__(256)
void panel_kernel(const float* __restrict__ e, _Float16* __restrict__ pan,
                  int N, int D) {
    const int p      = blockIdx.x >> 3;
    const int kwBase = (blockIdx.x & 7) * 8;
    #pragma unroll
    for (int it = 0; it < 4; ++it) {
        const int idx = it * 256 + threadIdx.x;   // 0..1023 = 8 kw x 128 r
        const int kw  = kwBase + (idx >> 7);
        const int r   = idx & 127;
        const float* src = &e[(size_t)(p * 128 + r) * D + kw * 8];
        const float4 x0 = *(const float4*)src;
        const float4 x1 = *(const float4*)(src + 4);
        const float xv[8] = {x0.x, x0.y, x0.z, x0.w, x1.x, x1.y, x1.z, x1.w};
        half8 hi, lo;
        #pragma unroll
        for (int j = 0; j < 8; ++j) {
            _Float16 h = (_Float16)xv[j];
            hi[j] = h;
            lo[j] = (_Float16)(xv[j] - (float)h);
        }
        *(half8*)&pan[((size_t)(p * 128 + kw) * 128 + r) * 8]      = hi;
        *(half8*)&pan[((size_t)(p * 128 + 64 + kw) * 128 + r) * 8] = lo;
    }
}

// Fused two-phase kernel. Tile 128x128, 4 waves each 64x64 (2x2 of 32x32x16 f16).
// dot = sum_k (hi.hi + hi.lo + lo.hi); acc retained across a per-row-panel barrier.
__global__ __launch_bounds__(256, 4)
void fused_kernel(const _Float16* __restrict__ pan, const int* __restrict__ labels,
                  const float* __restrict__ sq,
                  unsigned int* __restrict__ hp,
                  unsigned int* __restrict__ hn_fall,
                  unsigned int* __restrict__ hn_semi,
                  unsigned int* __restrict__ bars,
                  int N, int D, unsigned int nrowblocks) {
    // LDS frag layout [kcl(8)][r(128)][8 halves]: kcl<4 hi chunks, kcl>=4 lo chunks
    __shared__ __attribute__((aligned(16))) _Float16 As[8 * 128 * 8];
    __shared__ __attribute__((aligned(16))) _Float16 Bs[8 * 128 * 8];
    __shared__ float sq_r[128], sq_c[128], hp_r[128];
    __shared__ int   lab_r[128], lab_c[128];

    const int tid  = threadIdx.x;
    const int lane = tid & 63;
    const int wave = tid >> 6;
    const int wr = (wave >> 1) * 64;     // wave row offset
    const int wc = (wave & 1) * 64;      // wave col offset
    const int mrow = lane & 31;
    const int half_id = lane >> 5;
    const int py = blockIdx.y, px = blockIdx.x;
    const int rowBase = py * 128;
    const int colBase = px * 128;

    if (tid < 128) {
        sq_r[tid]  = sq[rowBase + tid];
        lab_r[tid] = labels[rowBase + tid];
    } else {
        int t = tid - 128;
        sq_c[t]  = sq[colBase + t];
        lab_c[t] = labels[colBase + t];
    }

    floatx16 acc[2][2];
    #pragma unroll
    for (int i = 0; i < 2; ++i)
        #pragma unroll
        for (int j = 0; j < 2; ++j)
            #pragma unroll
            for (int r = 0; r < 16; ++r) acc[i][j][r] = 0.f;

    #pragma unroll 1
    for (int kc0 = 0; kc0 < 64; kc0 += 4) {     // 16 iterations, BK = 32 halves
        __syncthreads();
        // 32 DMAs/block: wave w stages chunk kcl=w for all (ab, hilo, h) combos.
        // global side: lane-contiguous 1KB slab; LDS side: uniform base (+lane*16).
        #pragma unroll
        for (int i = 0; i < 8; ++i) {
            const int ab = i >> 2, hilo = (i >> 1) & 1, h = i & 1;
            const int p  = ab ? px : py;
            const int kc = hilo * 64 + kc0 + wave;
            const _Float16* g = pan + ((size_t)(p * 128 + kc) * 128 + h * 64 + lane) * 8;
            _Float16* l = (ab ? Bs : As) + ((hilo * 4 + wave) * 128 + h * 64) * 8;
            GLD_LDS16(g, l);
        }
        __syncthreads();                          // waits vmcnt(0): DMA complete
        #pragma unroll
        for (int ks = 0; ks < 2; ++ks) {
            const int kh = ks * 2 + half_id;      // hi chunk 0..3 (lo = +4)
            const half8 ah0 = *(const half8*)&As[(kh * 128 + wr + mrow) * 8];
            const half8 ah1 = *(const half8*)&As[(kh * 128 + wr + 32 + mrow) * 8];
            const half8 al0 = *(const half8*)&As[((kh + 4) * 128 + wr + mrow) * 8];
            const half8 al1 = *(const half8*)&As[((kh + 4) * 128 + wr + 32 + mrow) * 8];
            const half8 bh0 = *(const half8*)&Bs[(kh * 128 + wc + mrow) * 8];
            const half8 bh1 = *(const half8*)&Bs[(kh * 128 + wc + 32 + mrow) * 8];
            const half8 bl0 = *(const half8*)&Bs[((kh + 4) * 128 + wc + mrow) * 8];
            const half8 bl1 = *(const half8*)&Bs[((kh + 4) * 128 + wc + 32 + mrow) * 8];
            acc[0][0] = __builtin_amdgcn_mfma_f32_32x32x16_f16(ah0, bh0, acc[0][0], 0, 0, 0);
            acc[0][1] = __builtin_amdgcn_mfma_f32_32x32x16_f16(ah0, bh1, acc[0][1], 0, 0, 0);
            acc[1][0] = __builtin_amdgcn_mfma_f32_32x32x16_f16(ah1, bh0, acc[1][0], 0, 0, 0);
            acc[1][1] = __builtin_amdgcn_mfma_f32_32x32x16_f16(ah1, bh1, acc[1][1], 0, 0, 0);
            acc[0][0] = __builtin_amdgcn_mfma_f32_32x32x16_f16(ah0, bl0, acc[0][0], 0, 0, 0);
            acc[0][1] = __builtin_amdgcn_mfma_f32_32x32x16_f16(ah0, bl1, acc[0][1], 0, 0, 0);
            acc[1][0] = __builtin_amdgcn_mfma_f32_32x32x16_f16(ah1, bl0, acc[1][0], 0, 0, 0);
            acc[1][1] = __builtin_amdgcn_mfma_f32_32x32x16_f16(ah1, bl1, acc[1][1], 0, 0, 0);
            acc[0][0] = __builtin_amdgcn_mfma_f32_32x32x16_f16(al0, bh0, acc[0][0], 0, 0, 0);
            acc[0][1] = __builtin_amdgcn_mfma_f32_32x32x16_f16(al0, bh1, acc[0][1], 0, 0, 0);
            acc[1][0] = __builtin_amdgcn_mfma_f32_32x32x16_f16(al1, bh0, acc[1][0], 0, 0, 0);
            acc[1][1] = __builtin_amdgcn_mfma_f32_32x32x16_f16(al1, bh1, acc[1][1], 0, 0, 0);
        }
    }

    // per-lane column metadata (C/D layout: col = mrow within each 32-col frag)
    float sqcv[2]; int lcv[2];
    sqcv[0] = sq_c[wc + mrow];      lcv[0] = lab_c[wc + mrow];
    sqcv[1] = sq_c[wc + 32 + mrow]; lcv[1] = lab_c[wc + 32 + mrow];

    // ---- phase 1: hp (hardest positive), hn_fall (hardest negative) row maxima ----
    #pragma unroll
    for (int bi = 0; bi < 2; ++bi) {
        #pragma unroll
        for (int r = 0; r < 16; ++r) {
            const int lrow = wr + bi * 32 + (r & 3) + 8 * (r >> 2) + 4 * half_id;
            const float sqr = sq_r[lrow];
            const int   lr  = lab_r[lrow];
            float d0 = sqrtf(fmaxf(sqr + sqcv[0] - 2.0f * acc[bi][0][r], 1e-12f));
            float d1 = sqrtf(fmaxf(sqr + sqcv[1] - 2.0f * acc[bi][1][r], 1e-12f));
            const bool p0 = (lr == lcv[0]), p1 = (lr == lcv[1]);
            float vp = fmaxf(p0 ? d0 : 0.f, p1 ? d1 : 0.f);
            float vn = fmaxf(p0 ? 0.f : d0, p1 ? 0.f : d1);
            #pragma unroll
            for (int off = 16; off; off >>= 1) {   // reduce over 32 cols (half-wave)
                vp = fmaxf(vp, __shfl_xor(vp, off, 64));
                vn = fmaxf(vn, __shfl_xor(vn, off, 64));
            }
            if (mrow == 0) {
                atomicMax(&hp[rowBase + lrow],      __float_as_uint(vp));
                atomicMax(&hn_fall[rowBase + lrow], __float_as_uint(vn));
            }
        }
    }

    // ---- per-row-panel barrier: wait for the 32 blocks of grid-row py ----
    __syncthreads();                 // each wave drains its own atomics (vmcnt(0))
    unsigned int* ctr = &bars[py * 32];
    if (tid == 0) {
        __threadfence();
        atomicAdd(ctr, 1u);          // arrive (single RMW)
        while (__hip_atomic_load(ctr, __ATOMIC_ACQUIRE, __HIP_MEMORY_SCOPE_AGENT)
               < nrowblocks)
            __builtin_amdgcn_s_sleep(32);   // ~2k cyc backoff, load-only polling
    }
    __syncthreads();
    if (tid < 128)                   // coherent read of completed hp (no RMW)
        hp_r[tid] = __uint_as_float(__hip_atomic_load(&hp[rowBase + tid],
                                    __ATOMIC_RELAXED, __HIP_MEMORY_SCOPE_AGENT));
    __syncthreads();

    // ---- phase 2: hn_semi = min{d : neg, d > hp} from retained acc ----
    #pragma unroll
    for (int bi = 0; bi < 2; ++bi) {
        #pragma unroll
        for (int r = 0; r < 16; ++r) {
            const int lrow = wr + bi * 32 + (r & 3) + 8 * (r >> 2) + 4 * half_id;
            const float sqr = sq_r[lrow];
            const int   lr  = lab_r[lrow];
            const float hpv = hp_r[lrow];
            float d0 = sqrtf(fmaxf(sqr + sqcv[0] - 2.0f * acc[bi][0][r], 1e-12f));
            float d1 = sqrtf(fmaxf(sqr + sqcv[1] - 2.0f * acc[bi][1][r], 1e-12f));
            const bool c0 = (lr != lcv[0]) && (d0 > hpv);
            const bool c1 = (lr != lcv[1]) && (d1 > hpv);
            float vm = fminf(c0 ? d0 : __builtin_inff(), c1 ? d1 : __builtin_inff());
            #pragma unroll
            for (int off = 16; off; off >>= 1)
                vm = fminf(vm, __shfl_xor(vm, off, 64));
            if (mrow == 0)
                atomicMin(&hn_semi[rowBase + lrow], __float_as_uint(vm));
        }
    }
}

__global__ void final_kernel(const unsigned int* __restrict__ hp,
                             const unsigned int* __restrict__ hn_fall,
                             const unsigned int* __restrict__ hn_semi,
                             float* __restrict__ out, int N) {
    __shared__ float ssum[256];
    __shared__ int   scnt[256];
    __shared__ int   sany[256];
    int any = 0;
    for (int i = threadIdx.x; i < N; i += 256) {
        float h  = __uint_as_float(hp[i]);
        float hs = __uint_as_float(hn_semi[i]);
        any |= (hs < h + MARGIN) ? 1 : 0;   // exists semi-hard pair in this row
    }
    sany[threadIdx.x] = any;
    __syncthreads();
    for (int s = 128; s; s >>= 1) {
        if (threadIdx.x < (unsigned)s) sany[threadIdx.x] |= sany[threadIdx.x + s];
        __syncthreads();
    }
    const bool has_semi = sany[0] != 0;
    float sum = 0.f; int valid = 0;
    for (int i = threadIdx.x; i < N; i += 256) {
        float h  = __uint_as_float(hp[i]);
        float hn = has_semi ? __uint_as_float(hn_semi[i]) : __uint_as_float(hn_fall[i]);
        float t  = fmaxf(h - hn + MARGIN, 0.f);
        if (!(t > 0.f)) t = 0.f;            // -inf guard (hn=+inf rows)
        sum += t;
        valid += (t > 0.f) ? 1 : 0;
    }
    ssum[threadIdx.x] = sum; scnt[threadIdx.x] = valid;
    __syncthreads();
    for (int s = 128; s; s >>= 1) {
        if (threadIdx.x < (unsigned)s) {
            ssum[threadIdx.x] += ssum[threadIdx.x + s];
            scnt[threadIdx.x] += scnt[threadIdx.x + s];
        }
        __syncthreads();
    }
    if (threadIdx.x == 0) {
        float total = ssum[0]; int v = scnt[0];
        out[0] = (v > 0) ? (total / (float)v) : (total / (float)N);
    }
}

extern "C" void kernel_launch(void* const* d_in, const int* in_sizes, int n_in,
                              void* d_out, int out_size, void* d_ws, size_t ws_size,
                              hipStream_t stream) {
    const float* e      = (const float*)d_in[0];
    const int*   labels = (const int*)d_in[1];
    const int N = in_sizes[1];
    const int D = in_sizes[0] / N;
    float* out = (float*)d_out;

    float*        sq      = (float*)d_ws;
    unsigned int* hp      = (unsigned int*)d_ws + N;
    unsigned int* hn_fall = hp + N;
    unsigned int* hn_semi = hn_fall + N;
    unsigned int* bars    = hn_semi + N;     // 32 counters, 128B-spaced (1024 words)

    const size_t small_bytes = ((size_t)(4 * N + 1024) * 4 + 255) & ~(size_t)255;
    _Float16* pan = (_Float16*)((char*)d_ws + small_bytes);

    sq_init_kernel<<<N / 4, 256, 0, stream>>>(e, sq, hp, hn_fall, hn_semi, bars, N, D);
    panel_kernel<<<(N / 128) * 8, 256, 0, stream>>>(e, pan, N, D);

    dim3 grid(N / 128, N / 128);   // 32 x 32 = 1024 blocks = 4 per CU, co-resident
    fused_kernel<<<grid, 256, 0, stream>>>(pan, labels, sq, hp, hn_fall, hn_semi, bars,
                                           N, D, grid.x);
    final_kernel<<<1, 256, 0, stream>>>(hp, hn_fall, hn_semi, out, N);
}

// Round 8
// 160.948 us; speedup vs baseline: 1.8010x; 1.1443x over previous
//
#include <hip/hip_runtime.h>
#include <math.h>

// OnlineTripletLoss on MI355X — Round 8.
// R7: 184 us, fused 135 us, MfmaUtil 15%. Remaining gap attributed to (a) 512 MB of
//     panel staging traffic served cross-XCD at ~4.3 TB/s (blocks scattered, L2 thrash)
//     and (b) synchronized DMA bursts at the per-kk barrier with nothing to hide them.
// Changes:
//  (1) 256x256 tile, 1024 thr, grid 256 (1 block/CU): traffic 512->256 MB.
//  (2) double-buffered DMA (BK=16, 2x32KB = 64KB LDS exactly): one sync per kk; the
//      vmcnt(0) drain only covers prefetches issued a full compute-phase earlier.
//      Meta arrays reuse buffer LDS after the K loop.
//  (3) XCD swizzle (xcd = blockIdx & 7): each XCD's 32 blocks = 4x8 tile region; the
//      per-kk active slice set (~384 KB) becomes L2-resident.
// ws: sq[N] | hp[N] | hn_fall[N] | hn_semi[N] | bars[1024] | pad | pan[N*2D] f16

constexpr float MARGIN = 0.3f;

typedef _Float16 half8    __attribute__((ext_vector_type(8)));
typedef float    floatx16 __attribute__((ext_vector_type(16)));

#define GLD_LDS16(gp, lp)                                                              \
    __builtin_amdgcn_global_load_lds(                                                  \
        (const __attribute__((address_space(1))) void*)(gp),                           \
        (__attribute__((address_space(3))) void*)(lp), 16, 0, 0)

// sq + per-row init (one wave per row) + barrier-counter zeroing
__global__ __launch_bounds__(256)
void sq_init_kernel(const float* __restrict__ e, float* __restrict__ sq,
                    unsigned int* __restrict__ hp, unsigned int* __restrict__ hn_fall,
                    unsigned int* __restrict__ hn_semi, unsigned int* __restrict__ bars,
                    int N, int D) {
    if (blockIdx.x == 0 && threadIdx.x < 32) bars[threadIdx.x * 32] = 0u;
    const int row  = blockIdx.x * 4 + (threadIdx.x >> 6);
    const int lane = threadIdx.x & 63;
    if (row >= N) return;
    const float* er = e + (size_t)row * D;
    float s = 0.f;
    for (int k0 = lane * 8; k0 < D; k0 += 512) {
        const float4 x0 = *(const float4*)&er[k0];
        const float4 x1 = *(const float4*)&er[k0 + 4];
        s += x0.x*x0.x + x0.y*x0.y + x0.z*x0.z + x0.w*x0.w
           + x1.x*x1.x + x1.y*x1.y + x1.z*x1.z + x1.w*x1.w;
    }
    #pragma unroll
    for (int off = 32; off; off >>= 1) s += __shfl_down(s, off, 64);
    if (lane == 0) {
        sq[row]      = s;
        hp[row]      = 0u;           // max identity (dist >= 0)
        hn_fall[row] = 0u;
        hn_semi[row] = 0x7f800000u;  // +inf (min identity)
    }
}

// panel format: pan[p][kc][r][8] halves, p = 128-row panel, kc in [0,128):
// kc<64 = hi chunk of k-window kc*8, kc>=64 = lo chunk of (kc-64)*8.
__global__ __launch_bounds__(256)
void panel_kernel(const float* __restrict__ e, _Float16* __restrict__ pan,
                  int N, int D) {
    const int p      = blockIdx.x >> 3;
    const int kwBase = (blockIdx.x & 7) * 8;
    #pragma unroll
    for (int it = 0; it < 4; ++it) {
        const int idx = it * 256 + threadIdx.x;   // 0..1023 = 8 kw x 128 r
        const int kw  = kwBase + (idx >> 7);
        const int r   = idx & 127;
        const float* src = &e[(size_t)(p * 128 + r) * D + kw * 8];
        const float4 x0 = *(const float4*)src;
        const float4 x1 = *(const float4*)(src + 4);
        const float xv[8] = {x0.x, x0.y, x0.z, x0.w, x1.x, x1.y, x1.z, x1.w};
        half8 hi, lo;
        #pragma unroll
        for (int j = 0; j < 8; ++j) {
            _Float16 h = (_Float16)xv[j];
            hi[j] = h;
            lo[j] = (_Float16)(xv[j] - (float)h);
        }
        *(half8*)&pan[((size_t)(p * 128 + kw) * 128 + r) * 8]      = hi;
        *(half8*)&pan[((size_t)(p * 128 + 64 + kw) * 128 + r) * 8] = lo;
    }
}

// Fused two-phase kernel. Tile 256x256, 16 waves in a 4x4 grid, each 64x64
// (2x2 of 32x32x16 f16). Double-buffered DMA staging, one sync per kk.
__global__ __launch_bounds__(1024)
void fused_kernel(const _Float16* __restrict__ pan, const int* __restrict__ labels,
                  const float* __restrict__ sq,
                  unsigned int* __restrict__ hp,
                  unsigned int* __restrict__ hn_fall,
                  unsigned int* __restrict__ hn_semi,
                  unsigned int* __restrict__ bars,
                  int N, int D, unsigned int nrowblocks) {
    // 2 buffers x 32KB. Per buffer: [side A|B][plane sp*4+kcl (8)][r (128)][8 halves]
    // kcl 0,1 = hi chunks (2kk, 2kk+1); kcl 2,3 = lo chunks (64+2kk, 64+2kk+1).
    __shared__ __attribute__((aligned(16))) _Float16 S[32768];   // 64 KB exactly

    const int tid  = threadIdx.x;
    const int lane = tid & 63;
    const int wave = tid >> 6;           // 0..15
    const int wy = wave >> 2, wx = wave & 3;
    const int wr = wy * 64, wc = wx * 64;
    const int mrow = lane & 31;
    const int half_id = lane >> 5;

    // XCD swizzle: xcd j = blockIdx&7 gets a 4(px) x 8(py) region of the 16x16 grid
    const int j  = blockIdx.x & 7;
    const int i  = blockIdx.x >> 3;
    const int px = ((j & 3) << 2) | (i & 3);
    const int py = ((j >> 2) << 3) | (i >> 2);
    const int rowBase = py * 256;
    const int colBase = px * 256;

    floatx16 acc[2][2];
    #pragma unroll
    for (int a = 0; a < 2; ++a)
        #pragma unroll
        for (int b = 0; b < 2; ++b)
            #pragma unroll
            for (int r = 0; r < 16; ++r) acc[a][b][r] = 0.f;

    // staging: 32 slabs of 1KB per stage; wave w issues slabs 2w, 2w+1
    const int s0   = wave * 2;
    const int side = s0 >> 4, sp = (s0 >> 3) & 1, kcl = (s0 >> 1) & 3;
    const int pbase = (side ? 2 * px : 2 * py) + sp;
    const size_t gslab = ((size_t)pbase * 128) * 128;            // panel base (x8 halves)
    const int lplane = (side * 8 + sp * 4 + kcl) * 1024;         // LDS plane base (halves)

    #define STAGE(bufsel, kkv)                                                         \
        do {                                                                           \
            const int kc_ = (kcl < 2) ? (2 * (kkv) + kcl) : (64 + 2 * (kkv) + kcl - 2);\
            const _Float16* g_ = pan + (gslab + (size_t)kc_ * 128 + lane) * 8;         \
            GLD_LDS16(g_,       &S[(bufsel) * 16384 + lplane]);                        \
            GLD_LDS16(g_ + 512, &S[(bufsel) * 16384 + lplane + 512]);                  \
        } while (0)
    // two DMAs: rows 0-63 (lane) and 64-127 (lane+64 rows = +512 halves... g+64*8)

    // NOTE: second slab is rows 64..127: global offset += 64*8 halves = 512, LDS += 512*... 
    // (both handled above: +512 halves on each side)

    STAGE(0, 0);                                   // prologue prefetch

    #pragma unroll 1
    for (int kk = 0; kk < 32; ++kk) {
        const int buf = kk & 1;
        __syncthreads();                           // drains prefetch issued 1 compute ago
        if (kk + 1 < 32) STAGE(buf ^ 1, kk + 1);   // prefetch next into other buffer
        // compute from buf
        const int aB = buf * 16384 + ((wy >> 1) * 4 + half_id) * 1024 + ((wy & 1) * 64) * 8;
        const int bB = buf * 16384 + 8192 + ((wx >> 1) * 4 + half_id) * 1024 + ((wx & 1) * 64) * 8;
        const half8 ah0 = *(const half8*)&S[aB + mrow * 8];
        const half8 ah1 = *(const half8*)&S[aB + (32 + mrow) * 8];
        const half8 al0 = *(const half8*)&S[aB + 2048 + mrow * 8];
        const half8 al1 = *(const half8*)&S[aB + 2048 + (32 + mrow) * 8];
        const half8 bh0 = *(const half8*)&S[bB + mrow * 8];
        const half8 bh1 = *(const half8*)&S[bB + (32 + mrow) * 8];
        const half8 bl0 = *(const half8*)&S[bB + 2048 + mrow * 8];
        const half8 bl1 = *(const half8*)&S[bB + 2048 + (32 + mrow) * 8];
        acc[0][0] = __builtin_amdgcn_mfma_f32_32x32x16_f16(ah0, bh0, acc[0][0], 0, 0, 0);
        acc[0][1] = __builtin_amdgcn_mfma_f32_32x32x16_f16(ah0, bh1, acc[0][1], 0, 0, 0);
        acc[1][0] = __builtin_amdgcn_mfma_f32_32x32x16_f16(ah1, bh0, acc[1][0], 0, 0, 0);
        acc[1][1] = __builtin_amdgcn_mfma_f32_32x32x16_f16(ah1, bh1, acc[1][1], 0, 0, 0);
        acc[0][0] = __builtin_amdgcn_mfma_f32_32x32x16_f16(ah0, bl0, acc[0][0], 0, 0, 0);
        acc[0][1] = __builtin_amdgcn_mfma_f32_32x32x16_f16(ah0, bl1, acc[0][1], 0, 0, 0);
        acc[1][0] = __builtin_amdgcn_mfma_f32_32x32x16_f16(ah1, bl0, acc[1][0], 0, 0, 0);
        acc[1][1] = __builtin_amdgcn_mfma_f32_32x32x16_f16(ah1, bl1, acc[1][1], 0, 0, 0);
        acc[0][0] = __builtin_amdgcn_mfma_f32_32x32x16_f16(al0, bh0, acc[0][0], 0, 0, 0);
        acc[0][1] = __builtin_amdgcn_mfma_f32_32x32x16_f16(al0, bh1, acc[0][1], 0, 0, 0);
        acc[1][0] = __builtin_amdgcn_mfma_f32_32x32x16_f16(al1, bh0, acc[1][0], 0, 0, 0);
        acc[1][1] = __builtin_amdgcn_mfma_f32_32x32x16_f16(al1, bh1, acc[1][1], 0, 0, 0);
    }

    // ---- reuse buffer LDS for epilogue metadata ----
    __syncthreads();
    float* F = (float*)S;           // [0,256) sq_r | [256,512) sq_c | [512,768) hp_r
    int*   L = (int*)(F + 768);     // [0,256) lab_r | [256,512) lab_c
    if (tid < 256) {
        F[tid]       = sq[rowBase + tid];
        L[tid]       = labels[rowBase + tid];
    } else if (tid < 512) {
        const int t = tid - 256;
        F[256 + t]   = sq[colBase + t];
        L[256 + t]   = labels[colBase + t];
    }
    __syncthreads();

    float sqcv[2]; int lcv[2];
    sqcv[0] = F[256 + wc + mrow];      lcv[0] = L[256 + wc + mrow];
    sqcv[1] = F[256 + wc + 32 + mrow]; lcv[1] = L[256 + wc + 32 + mrow];

    // ---- phase 1: hp / hn_fall row maxima ----
    #pragma unroll
    for (int bi = 0; bi < 2; ++bi) {
        #pragma unroll
        for (int r = 0; r < 16; ++r) {
            const int lrow = wr + bi * 32 + (r & 3) + 8 * (r >> 2) + 4 * half_id;
            const float sqr = F[lrow];
            const int   lr  = L[lrow];
            float d0 = sqrtf(fmaxf(sqr + sqcv[0] - 2.0f * acc[bi][0][r], 1e-12f));
            float d1 = sqrtf(fmaxf(sqr + sqcv[1] - 2.0f * acc[bi][1][r], 1e-12f));
            const bool p0 = (lr == lcv[0]), p1 = (lr == lcv[1]);
            float vp = fmaxf(p0 ? d0 : 0.f, p1 ? d1 : 0.f);
            float vn = fmaxf(p0 ? 0.f : d0, p1 ? 0.f : d1);
            #pragma unroll
            for (int off = 16; off; off >>= 1) {
                vp = fmaxf(vp, __shfl_xor(vp, off, 64));
                vn = fmaxf(vn, __shfl_xor(vn, off, 64));
            }
            if (mrow == 0) {
                atomicMax(&hp[rowBase + lrow],      __float_as_uint(vp));
                atomicMax(&hn_fall[rowBase + lrow], __float_as_uint(vn));
            }
        }
    }

    // ---- per-row-panel barrier: the 16 blocks sharing py ----
    __syncthreads();
    unsigned int* ctr = &bars[py * 32];
    if (tid == 0) {
        __threadfence();
        atomicAdd(ctr, 1u);
        while (__hip_atomic_load(ctr, __ATOMIC_ACQUIRE, __HIP_MEMORY_SCOPE_AGENT)
               < nrowblocks)
            __builtin_amdgcn_s_sleep(32);
    }
    __syncthreads();
    if (tid < 256)
        F[512 + tid] = __uint_as_float(__hip_atomic_load(&hp[rowBase + tid],
                                       __ATOMIC_RELAXED, __HIP_MEMORY_SCOPE_AGENT));
    __syncthreads();

    // ---- phase 2: hn_semi = min{d : neg, d > hp} from retained acc ----
    #pragma unroll
    for (int bi = 0; bi < 2; ++bi) {
        #pragma unroll
        for (int r = 0; r < 16; ++r) {
            const int lrow = wr + bi * 32 + (r & 3) + 8 * (r >> 2) + 4 * half_id;
            const float sqr = F[lrow];
            const int   lr  = L[lrow];
            const float hpv = F[512 + lrow];
            float d0 = sqrtf(fmaxf(sqr + sqcv[0] - 2.0f * acc[bi][0][r], 1e-12f));
            float d1 = sqrtf(fmaxf(sqr + sqcv[1] - 2.0f * acc[bi][1][r], 1e-12f));
            const bool c0 = (lr != lcv[0]) && (d0 > hpv);
            const bool c1 = (lr != lcv[1]) && (d1 > hpv);
            float vm = fminf(c0 ? d0 : __builtin_inff(), c1 ? d1 : __builtin_inff());
            #pragma unroll
            for (int off = 16; off; off >>= 1)
                vm = fminf(vm, __shfl_xor(vm, off, 64));
            if (mrow == 0)
                atomicMin(&hn_semi[rowBase + lrow], __float_as_uint(vm));
        }
    }
}

__global__ void final_kernel(const unsigned int* __restrict__ hp,
                             const unsigned int* __restrict__ hn_fall,
                             const unsigned int* __restrict__ hn_semi,
                             float* __restrict__ out, int N) {
    __shared__ float ssum[256];
    __shared__ int   scnt[256];
    __shared__ int   sany[256];
    int any = 0;
    for (int i = threadIdx.x; i < N; i += 256) {
        float h  = __uint_as_float(hp[i]);
        float hs = __uint_as_float(hn_semi[i]);
        any |= (hs < h + MARGIN) ? 1 : 0;   // exists semi-hard pair in this row
    }
    sany[threadIdx.x] = any;
    __syncthreads();
    for (int s = 128; s; s >>= 1) {
        if (threadIdx.x < (unsigned)s) sany[threadIdx.x] |= sany[threadIdx.x + s];
        __syncthreads();
    }
    const bool has_semi = sany[0] != 0;
    float sum = 0.f; int valid = 0;
    for (int i = threadIdx.x; i < N; i += 256) {
        float h  = __uint_as_float(hp[i]);
        float hn = has_semi ? __uint_as_float(hn_semi[i]) : __uint_as_float(hn_fall[i]);
        float t  = fmaxf(h - hn + MARGIN, 0.f);
        if (!(t > 0.f)) t = 0.f;            // -inf guard (hn=+inf rows)
        sum += t;
        valid += (t > 0.f) ? 1 : 0;
    }
    ssum[threadIdx.x] = sum; scnt[threadIdx.x] = valid;
    __syncthreads();
    for (int s = 128; s; s >>= 1) {
        if (threadIdx.x < (unsigned)s) {
            ssum[threadIdx.x] += ssum[threadIdx.x + s];
            scnt[threadIdx.x] += scnt[threadIdx.x + s];
        }
        __syncthreads();
    }
    if (threadIdx.x == 0) {
        float total = ssum[0]; int v = scnt[0];
        out[0] = (v > 0) ? (total / (float)v) : (total / (float)N);
    }
}

extern "C" void kernel_launch(void* const* d_in, const int* in_sizes, int n_in,
                              void* d_out, int out_size, void* d_ws, size_t ws_size,
                              hipStream_t stream) {
    const float* e      = (const float*)d_in[0];
    const int*   labels = (const int*)d_in[1];
    const int N = in_sizes[1];
    const int D = in_sizes[0] / N;
    float* out = (float*)d_out;

    float*        sq      = (float*)d_ws;
    unsigned int* hp      = (unsigned int*)d_ws + N;
    unsigned int* hn_fall = hp + N;
    unsigned int* hn_semi = hn_fall + N;
    unsigned int* bars    = hn_semi + N;     // 32 counters, 128B-spaced (1024 words)

    const size_t small_bytes = ((size_t)(4 * N + 1024) * 4 + 255) & ~(size_t)255;
    _Float16* pan = (_Float16*)((char*)d_ws + small_bytes);

    sq_init_kernel<<<N / 4, 256, 0, stream>>>(e, sq, hp, hn_fall, hn_semi, bars, N, D);
    panel_kernel<<<(N / 128) * 8, 256, 0, stream>>>(e, pan, N, D);

    const int nt = N / 256;                  // 16x16 tile grid, XCD-swizzled 1D launch
    fused_kernel<<<nt * nt, 1024, 0, stream>>>(pan, labels, sq, hp, hn_fall, hn_semi,
                                               bars, N, D, (unsigned)nt);
    final_kernel<<<1, 256, 0, stream>>>(hp, hn_fall, hn_semi, out, N);
}